// Round 20
// baseline (78.209 us; speedup 1.0000x reference)
//
#include <hip/hip_runtime.h>

#define EPS 1e-7f
#define NCH 29
#define SPB 128          // samples per block: 64 lanes x 2 packed (group0, group1)
#define CPC 6            // channels per chunk (one per compute wave)
#define NCHUNK 5         // 5 chunks x 6 = 30 >= 29 channels
#define ROWB 13          // padded f4 stride per sample per buffer (12 + 1)

// Producer-consumer wave specialization:
//   waves 0..5  = compute (channel c = chunk*6 + wid, wave-uniform -> SGPR weights)
//   waves 6..7  = store   (flush previous chunk's buffer to global)
// Double-buffered obuf; lgkm-only barrier per phase. Store-issue backpressure
// (the R18/R19 finding: saturated L2 write path stalls stores AT ISSUE) now
// lands on dedicated store waves while compute waves keep issuing VALU.

typedef float f32x2 __attribute__((ext_vector_type(2)));
typedef float nf4   __attribute__((ext_vector_type(4)));

__device__ __forceinline__ f32x2 splat2(float v) { f32x2 r; r.x = v; r.y = v; return r; }
__device__ __forceinline__ f32x2 fma2(f32x2 a, f32x2 b, f32x2 c) {
    return __builtin_elementwise_fma(a, b, c);
}
__device__ __forceinline__ f32x2 max2(f32x2 a, f32x2 b) {
    return __builtin_elementwise_max(a, b);
}
__device__ __forceinline__ f32x2 expc2(f32x2 a) {
    f32x2 r; r.x = __expf(a.x); r.y = __expf(a.y); return r;
}
__device__ __forceinline__ f32x2 rcp2(f32x2 a) {
    f32x2 r; r.x = __builtin_amdgcn_rcpf(a.x); r.y = __builtin_amdgcn_rcpf(a.y); return r;
}
__device__ __forceinline__ nf4 mk4(float a, float b, float c, float d) {
    nf4 r; r.x = a; r.y = b; r.z = c; r.w = d; return r;
}

// Barrier ordering LDS traffic only (lgkmcnt), NOT global stores (vmcnt).
__device__ __forceinline__ void barrier_lds_only() {
    asm volatile("s_waitcnt lgkmcnt(0)\n\ts_barrier" ::: "memory");
}

// Packed 2-sample MLP: weights wave-uniform (SGPR), data f32x2.
__device__ __forceinline__ void mlp7p(const f32x2 x[7],
    const float* __restrict__ W0, const float* __restrict__ b0,
    const float* __restrict__ W1, const float* __restrict__ b1,
    const float* __restrict__ W2, const float* __restrict__ b2,
    const float* __restrict__ W3, const float* __restrict__ b3,
    f32x2 e[3])
{
    const f32x2 zero = splat2(0.0f);
    f32x2 h0[5];
#pragma unroll
    for (int h = 0; h < 5; ++h) {
        f32x2 a = splat2(b0[h]);
#pragma unroll
        for (int f = 0; f < 7; ++f) a = fma2(x[f], splat2(W0[f * 5 + h]), a);
        h0[h] = max2(a, zero);
    }
    f32x2 h1[4];
#pragma unroll
    for (int k = 0; k < 4; ++k) {
        f32x2 a = splat2(b1[k]);
#pragma unroll
        for (int h = 0; h < 5; ++h) a = fma2(h0[h], splat2(W1[h * 4 + k]), a);
        h1[k] = max2(a, zero);
    }
    f32x2 h2[4];
#pragma unroll
    for (int k = 0; k < 4; ++k) {
        f32x2 a = splat2(b2[k]);
#pragma unroll
        for (int h = 0; h < 4; ++h) a = fma2(h1[h], splat2(W2[h * 4 + k]), a);
        h2[k] = max2(a, zero);
    }
    f32x2 l[3];
#pragma unroll
    for (int k = 0; k < 3; ++k) {
        f32x2 a = splat2(b3[k]);
#pragma unroll
        for (int h = 0; h < 4; ++h) a = fma2(h2[h], splat2(W3[h * 3 + k]), a);
        l[k] = a;
    }
    f32x2 m = max2(l[0], max2(l[1], l[2]));
    f32x2 e0 = expc2(l[0] - m);
    f32x2 e1 = expc2(l[1] - m);
    f32x2 e2 = expc2(l[2] - m);
    f32x2 rs = rcp2(e0 + e1 + e2);
    e[0] = e0 * rs; e[1] = e1 * rs; e[2] = e2 * rs;
}

// 2 blocks/CU: LDS 2 x 53.2KB = 106.4KB, VGPR cap 128 (4 waves/EU).
__global__ __launch_bounds__(512, 4) void lps_kernel(
    const float* __restrict__ tau, const float* __restrict__ mu, const float* __restrict__ mu_bar,
    const float* __restrict__ lw, const float* __restrict__ h2o, const float* __restrict__ o3,
    const float* __restrict__ co2, const float* __restrict__ uu, const float* __restrict__ n2o,
    const float* __restrict__ ch4,
    const float* __restrict__ Wd0, const float* __restrict__ bd0,
    const float* __restrict__ Wf0, const float* __restrict__ bf0,
    const float* __restrict__ Wd1, const float* __restrict__ bd1,
    const float* __restrict__ Wf1, const float* __restrict__ bf1,
    const float* __restrict__ Wd2, const float* __restrict__ bd2,
    const float* __restrict__ Wf2, const float* __restrict__ bf2,
    const float* __restrict__ Wd3, const float* __restrict__ bd3,
    const float* __restrict__ Wf3, const float* __restrict__ bf3,
    float* __restrict__ out, int N)
{
    __shared__ __align__(16) nf4 obuf[2][SPB][ROWB];   // 53248 B

    const int tid  = threadIdx.x;
    const int lane = tid & 63;
    const int wid  = __builtin_amdgcn_readfirstlane(tid >> 6);   // 0..7

    const long long base = (long long)blockIdx.x * SPB;
    int nsamp = N - (int)base;
    if (nsamp > SPB) nsamp = SPB;
    nf4* out4 = (nf4*)out;

    // ---- compute-wave per-lane state (waves 0..5) ----
    const int s0 = (int)base + lane;
    const int s1 = s0 + 64;
    const int i0 = (s0 < N) ? s0 : (N - 1);
    const int i1 = (s1 < N) ? s1 : (N - 1);

    f32x2 rmu2 = splat2(1.0f), rmub2 = splat2(1.0f);
    f32x2 cons2[7];
    f32x2 tau2v[NCHUNK];
#pragma unroll
    for (int k = 0; k < NCHUNK; ++k) tau2v[k] = splat2(0.0f);

    if (wid < CPC) {
        f32x2 mu2, mub2;
        mu2.x  = mu[i0];      mu2.y  = mu[i1];
        mub2.x = mu_bar[i0];  mub2.y = mu_bar[i1];
        rmu2  = rcp2(mu2 + splat2(EPS));
        rmub2 = rcp2(mub2 + splat2(EPS));

        cons2[0].x = lw[i0];  cons2[0].y = lw[i1];
        cons2[1].x = h2o[i0]; cons2[1].y = h2o[i1];
        cons2[2].x = o3[i0];  cons2[2].y = o3[i1];
        cons2[3].x = co2[i0]; cons2[3].y = co2[i1];
        cons2[4].x = uu[i0];  cons2[4].y = uu[i1];
        cons2[5].x = n2o[i0]; cons2[5].y = n2o[i1];
        cons2[6].x = ch4[i0]; cons2[6].y = ch4[i1];

        // hoist ALL tau loads before any store exists (keeps the loop vmem-free)
#pragma unroll
        for (int k = 0; k < NCHUNK; ++k) {
            const int c  = k * CPC + wid;
            const int cc = (c < NCH) ? c : 0;
            tau2v[k].x = tau[(size_t)i0 * NCH + cc];
            tau2v[k].y = tau[(size_t)i1 * NCH + cc];
        }
    }

    const int st = tid - CPC * 64;   // store-thread index 0..127 (waves 6,7)

    // ---- 6 phases: p in [0,5]; compute chunk p (p<5), flush chunk p-1 (p>=1) ----
#pragma unroll
    for (int p = 0; p <= NCHUNK; ++p) {
        if (p < NCHUNK && wid < CPC) {
            const int c = p * CPC + wid;      // wave-uniform channel
            if (c < NCH) {
                const f32x2 td2 = expc2(-(tau2v[p] * rmu2));
                const f32x2 tf2 = expc2(-(tau2v[p] * rmub2));

                f32x2 x2[7];
                f32x2 ed[3], ef[3];
#pragma unroll
                for (int f = 0; f < 7; ++f) x2[f] = cons2[f] * rmu2;
                mlp7p(x2, Wd0 + c * 35, bd0 + c * 5, Wd1 + c * 20, bd1 + c * 4,
                          Wd2 + c * 16, bd2 + c * 4, Wd3 + c * 12, bd3 + c * 3, ed);
#pragma unroll
                for (int f = 0; f < 7; ++f) x2[f] = cons2[f] * rmub2;
                mlp7p(x2, Wf0 + c * 35, bf0 + c * 5, Wf1 + c * 20, bf1 + c * 4,
                          Wf2 + c * 16, bf2 + c * 4, Wf3 + c * 12, bf3 + c * 3, ef);

                const int r = wid * 2;        // slot within chunk row (0..11)
                obuf[p & 1][lane][r]          = mk4(td2.x, tf2.x, ed[0].x, ed[1].x);
                obuf[p & 1][lane][r + 1]      = mk4(ed[2].x, ef[0].x, ef[1].x, ef[2].x);
                obuf[p & 1][lane + 64][r]     = mk4(td2.y, tf2.y, ed[0].y, ed[1].y);
                obuf[p & 1][lane + 64][r + 1] = mk4(ed[2].y, ef[0].y, ef[1].y, ef[2].y);
            }
        }

        if (p >= 1 && wid >= CPC && nsamp > 0) {
            const int it  = p - 1;                   // chunk being flushed
            const int cnt = (it < 4) ? 12 : 10;      // f4 per sample in this chunk
            const int tot = nsamp * cnt;
            for (int i = st; i < tot; i += 128) {
                const int s = i / cnt, rr = i - s * cnt;
                out4[(base + s) * 58 + it * 12 + rr] = obuf[it & 1][s][rr];
            }
        }

        barrier_lds_only();   // phase handoff (LDS ordering only; stores fly free)
    }
}

extern "C" void kernel_launch(void* const* d_in, const int* in_sizes, int n_in,
                              void* d_out, int out_size, void* d_ws, size_t ws_size,
                              hipStream_t stream) {
    const float* tau    = (const float*)d_in[0];
    const float* mu     = (const float*)d_in[1];
    const float* mu_bar = (const float*)d_in[2];
    const float* lw     = (const float*)d_in[3];
    const float* h2o    = (const float*)d_in[4];
    const float* o3     = (const float*)d_in[5];
    const float* co2    = (const float*)d_in[6];
    const float* uu     = (const float*)d_in[7];
    const float* n2o    = (const float*)d_in[8];
    const float* ch4    = (const float*)d_in[9];

    const float* Wd0 = (const float*)d_in[10];
    const float* bd0 = (const float*)d_in[11];
    const float* Wf0 = (const float*)d_in[12];
    const float* bf0 = (const float*)d_in[13];
    const float* Wd1 = (const float*)d_in[14];
    const float* bd1 = (const float*)d_in[15];
    const float* Wf1 = (const float*)d_in[16];
    const float* bf1 = (const float*)d_in[17];
    const float* Wd2 = (const float*)d_in[18];
    const float* bd2 = (const float*)d_in[19];
    const float* Wf2 = (const float*)d_in[20];
    const float* bf2 = (const float*)d_in[21];
    const float* Wd3 = (const float*)d_in[22];
    const float* bd3 = (const float*)d_in[23];
    const float* Wf3 = (const float*)d_in[24];
    const float* bf3 = (const float*)d_in[25];

    float* out = (float*)d_out;
    int N = in_sizes[1];  // mu has N elements

    int blocks = (N + SPB - 1) / SPB;
    lps_kernel<<<blocks, 512, 0, stream>>>(
        tau, mu, mu_bar, lw, h2o, o3, co2, uu, n2o, ch4,
        Wd0, bd0, Wf0, bf0, Wd1, bd1, Wf1, bf1,
        Wd2, bd2, Wf2, bf2, Wd3, bd3, Wf3, bf3,
        out, N);
}